// Round 8
// baseline (337.633 us; speedup 1.0000x reference)
//
#include <hip/hip_runtime.h>
#include <math.h>

// ReAttention round 8: NO S~ materialization. Attention = k_rsum (QK+exp+
// rowsum, zero-LDS zero-barrier) + k_fuse (recompute QK bitwise-identically,
// normalize, conv-mix, BN stats, PV). fp16 pipeline, fp32 accum/stats.
// B=8 N=1024 D=512 H=8 dh=64.
//
//  - conv bias cancels in train-mode BN (shifts mean only).
//  - attn'' = alpha_g*u_g + c_g ; u_g = sum_h conv_w[g,h]*S_h
//  - out_inner = alpha_g*O1 + c_g*vsum ; O1 = u @ v  (alpha-independent)
//  - R5 lesson: watch VGPR (spill -> phantom WRITE_SIZE).
//  - R6/R7 lesson: the 134MB S~ handoff is latency-bound at the consumer
//    regardless of L3 residency; recomputing QK (8.6 GF + 67M exp) is cheaper.

#define Bz 8
#define Nn 1024
#define Dd 512
#define Hh 8
#define DH 64
#define INNER 512
#define QW 1536
#define SCALE 0.125f
#define BN_EPS 1e-5f

typedef _Float16 __f16;
typedef __f16 f16x8 __attribute__((ext_vector_type(8)));
typedef float f32x4 __attribute__((ext_vector_type(4)));

#define MFMA16(a, b, c) __builtin_amdgcn_mfma_f32_16x16x32_f16((a), (b), (c), 0, 0, 0)

__device__ __forceinline__ unsigned short f2h(float f) {
  union { __f16 h; unsigned short s; } v;
  v.h = (__f16)f;
  return v.s;
}
__device__ __forceinline__ float h2f(unsigned short s) {
  union { unsigned short s; __f16 h; } v;
  v.s = s;
  return (float)v.h;
}

// ws layout (bytes) — flat, no overlays. total ~69.5 MB
#define WB_XB 0u                        // 8,388,608
#define WB_QKV 8388608u                 // 25,165,824
#define WB_VT 33554432u                 // 8,388,608
#define WB_O1 41943040u                 // 16,777,216 fp32
#define WB_O1BF 58720256u               // 8,388,608 fp16
#define WB_WQT 67108864u                // 1,572,864
#define WB_WOT 68681728u                // 524,288
#define WB_RINV 69206016u               // 262,144
#define WB_VSUM 69468160u               // 16,384
#define WB_STATS 69484544u              // 64
#define WB_AC 69484608u                 // 64

// ---------------- x -> fp16 ------------------------------------------------
__global__ __launch_bounds__(256) void k_xbf(const float* __restrict__ X,
                                             unsigned short* __restrict__ XB) {
  const size_t i = ((size_t)blockIdx.x * 256 + threadIdx.x) * 8;
  float4 f0 = *(const float4*)(X + i);
  float4 f1 = *(const float4*)(X + i + 4);
  unsigned short o[8] = {f2h(f0.x), f2h(f0.y), f2h(f0.z), f2h(f0.w),
                         f2h(f1.x), f2h(f1.y), f2h(f1.z), f2h(f1.w)};
  *(uint4*)(XB + i) = *(uint4*)o;
}

// ---------------- transpose fp32 -> fp16: dst[C][R] = src[R][C]^T ----------
__global__ __launch_bounds__(256) void k_transpose(const float* __restrict__ src,
                                                   unsigned short* __restrict__ dst,
                                                   int R, int C) {
  __shared__ float tile[32][33];
  const int tc = blockIdx.x * 32, tr = blockIdx.y * 32;
  const int lx = threadIdx.x & 31, ly = threadIdx.x >> 5;
#pragma unroll
  for (int i = 0; i < 32; i += 8)
    tile[ly + i][lx] = src[(size_t)(tr + ly + i) * C + tc + lx];
  __syncthreads();
#pragma unroll
  for (int i = 0; i < 32; i += 8)
    dst[(size_t)(tc + ly + i) * R + tr + lx] = f2h(tile[lx][ly + i]);
}

// ---------------- K0: qkv = x @ w_qkv (fp16 MFMA) --------------------------
__global__ __launch_bounds__(256) void k_qkv(const unsigned short* __restrict__ XB,
                                             const unsigned short* __restrict__ WQT,
                                             unsigned short* __restrict__ qkv,
                                             unsigned short* __restrict__ vT) {
  extern __shared__ char smem[];
  unsigned short(*sA)[40] = (unsigned short(*)[40])smem;
  unsigned short(*sB)[40] = (unsigned short(*)[40])(smem + 128 * 40 * 2);
  unsigned short* sEp = (unsigned short*)smem;  // 128*136 after loop
  const int t = threadIdx.x;
  const int col0 = blockIdx.x * 128;
  const int row0 = blockIdx.y * 128;
  const bool isqk = (col0 < 2 * INNER);
  const int l = t & 63, w = t >> 6;
  const int wm = (w & 1) * 64, wn = (w >> 1) * 64;
  const int lm = l & 15, lq = l >> 4;
  const int srow = t >> 1, skc = (t & 1) * 16;
  f32x4 acc[4][4] = {};
  for (int k0 = 0; k0 < Dd; k0 += 32) {
    {
      const unsigned short* src = XB + (size_t)(row0 + srow) * Dd + k0 + skc;
      *(uint4*)&sA[srow][skc] = *(const uint4*)src;
      *(uint4*)&sA[srow][skc + 8] = *(const uint4*)(src + 8);
    }
    {
      const unsigned short* srcB = WQT + (size_t)(col0 + srow) * Dd + k0 + skc;
      *(uint4*)&sB[srow][skc] = *(const uint4*)srcB;
      *(uint4*)&sB[srow][skc + 8] = *(const uint4*)(srcB + 8);
    }
    __syncthreads();
    f16x8 af[4], bfr[4];
#pragma unroll
    for (int i = 0; i < 4; i++) af[i] = *(const f16x8*)&sA[wm + 16 * i + lm][lq * 8];
#pragma unroll
    for (int j = 0; j < 4; j++) bfr[j] = *(const f16x8*)&sB[wn + 16 * j + lm][lq * 8];
    if (isqk) {
#pragma unroll
      for (int i = 0; i < 4; i++)
#pragma unroll
        for (int j = 0; j < 4; j++) acc[i][j] = MFMA16(bfr[i], af[j], acc[i][j]);
    } else {
#pragma unroll
      for (int i = 0; i < 4; i++)
#pragma unroll
        for (int j = 0; j < 4; j++) acc[i][j] = MFMA16(af[i], bfr[j], acc[i][j]);
    }
    __syncthreads();
  }
  if (isqk) {
#pragma unroll
    for (int jc = 0; jc < 4; jc++)
#pragma unroll
      for (int ir = 0; ir < 4; ir++) {
        unsigned short us[4];
#pragma unroll
        for (int r = 0; r < 4; r++) us[r] = f2h(acc[jc][ir][r]);
        *(uint2*)&sEp[(wm + 16 * ir + lm) * 136 + wn + 16 * jc + 4 * lq] = *(uint2*)us;
      }
    __syncthreads();
    const int row = t >> 1, half = t & 1;
    const unsigned short* src = &sEp[row * 136 + half * 64];
    unsigned short* dst = qkv + (size_t)(row0 + row) * QW + col0 + half * 64;
#pragma unroll
    for (int c = 0; c < 8; c++) *(uint4*)(dst + c * 8) = *(const uint4*)(src + c * 8);
  } else {
#pragma unroll
    for (int ir = 0; ir < 4; ir++)
#pragma unroll
      for (int jc = 0; jc < 4; jc++) {
        unsigned short us[4];
#pragma unroll
        for (int r = 0; r < 4; r++) us[r] = f2h(acc[ir][jc][r]);
        *(uint2*)&sEp[(wn + 16 * jc + lm) * 136 + wm + 16 * ir + 4 * lq] = *(uint2*)us;
      }
    __syncthreads();
    const int row = t >> 1, half = t & 1;
    const int gd = col0 - 2 * INNER + row;
    const int bq = row0 >> 10, mseq0 = row0 & 1023;
    const unsigned short* src = &sEp[row * 136 + half * 64];
    unsigned short* dst =
        vT + (((size_t)(bq * Hh + (gd >> 6)) * DH + (gd & 63)) << 10) + mseq0 + half * 64;
#pragma unroll
    for (int c = 0; c < 8; c++) *(uint4*)(dst + c * 8) = *(const uint4*)(src + c * 8);
  }
}

// ---------------- k_vsum --------------------------------------------------
__global__ __launch_bounds__(256) void k_vsum(const unsigned short* __restrict__ vT,
                                              float* __restrict__ vsum) {
  const int bg = blockIdx.x;
  const int d = threadIdx.x >> 2, qq = threadIdx.x & 3;
  __shared__ float red[64][4];
  const unsigned short* p = vT + ((size_t)bg * DH + d) * Nn + qq * 256;
  float s = 0.f;
  for (int m = 0; m < 256; m += 4) {
    uint2 rr = *(const uint2*)(p + m);
    s += h2f((unsigned short)(rr.x & 0xffff)) + h2f((unsigned short)(rr.x >> 16)) +
         h2f((unsigned short)(rr.y & 0xffff)) + h2f((unsigned short)(rr.y >> 16));
  }
  red[d][qq] = s;
  __syncthreads();
  if (threadIdx.x < 64)
    vsum[(size_t)bg * DH + threadIdx.x] =
        red[threadIdx.x][0] + red[threadIdx.x][1] + red[threadIdx.x][2] + red[threadIdx.x][3];
}

// ---------------- kA: row sums (zero LDS, zero barriers) -------------------
// grid (b=8, nt=64); 512 thr = 8 waves, wave w = head w, n-tile 16.
// Q frags in registers; K frags straight from L2-resident qkv.
__global__ __launch_bounds__(512, 2) void k_rsum(const unsigned short* __restrict__ qkv,
                                                 float* __restrict__ rinv) {
  const int b = blockIdx.x;  // b fastest -> XCD-pinned qkv slice
  const int n0 = blockIdx.y * 16;
  const int t = threadIdx.x;
  const int w = t >> 6, l = t & 63;
  const int lm = l & 15, lq = l >> 4;
  f16x8 qf[2];
  {
    const unsigned short* qp = qkv + (size_t)(b * Nn + n0 + lm) * QW + w * DH + lq * 8;
    qf[0] = *(const f16x8*)qp;
    qf[1] = *(const f16x8*)(qp + 32);
  }
  float psum[4] = {};
  for (int m0 = 0; m0 < Nn; m0 += 32) {
#pragma unroll
    for (int jm = 0; jm < 2; jm++) {
      const unsigned short* kp =
          qkv + (size_t)(b * Nn + m0 + 16 * jm + lm) * QW + INNER + w * DH + lq * 8;
      f16x8 k0 = *(const f16x8*)kp;
      f16x8 k1 = *(const f16x8*)(kp + 32);
      f32x4 lac = {};
      lac = MFMA16(qf[0], k0, lac);  // same chain order as k_fuse => bitwise equal
      lac = MFMA16(qf[1], k1, lac);
#pragma unroll
      for (int r = 0; r < 4; r++) psum[r] += __expf(lac[r] * SCALE);
    }
  }
#pragma unroll
  for (int r = 0; r < 4; r++) {
    float s = psum[r];
    s += __shfl_xor(s, 1);
    s += __shfl_xor(s, 2);
    s += __shfl_xor(s, 4);
    s += __shfl_xor(s, 8);
    if (lm == 0) rinv[(size_t)(b * Hh + w) * Nn + n0 + lq * 4 + r] = 1.0f / s;
  }
}

// ---------------- kB: recompute S + mix + stats + PV -----------------------
// grid (b=8, nt=64); 512 thr = 8 waves; wave w = head (QK) = group (PV).
__global__ __launch_bounds__(512, 2) void k_fuse(const unsigned short* __restrict__ qkv,
                                                 const unsigned short* __restrict__ vT,
                                                 const float* __restrict__ rinv,
                                                 const float* __restrict__ conv_w,
                                                 float* __restrict__ O1,
                                                 float* __restrict__ stats) {
  __shared__ __align__(16) unsigned short sS[8][16][36];  //  9,216 B
  __shared__ __align__(16) unsigned short sU[8][16][40];  // 10,240 B
  __shared__ float sRed[8][16];
  const int b = blockIdx.x;
  const int n0 = blockIdx.y * 16;
  const int t = threadIdx.x;
  const int w = t >> 6, l = t & 63;
  const int lm = l & 15, lq = l >> 4;
  const int mxn = t >> 5, mxm = t & 31;
  float cw[64];
#pragma unroll
  for (int i = 0; i < 64; i++) cw[i] = conv_w[i];  // uniform -> SGPRs
  f16x8 qf[2];
  {
    const unsigned short* qp = qkv + (size_t)(b * Nn + n0 + lm) * QW + w * DH + lq * 8;
    qf[0] = *(const f16x8*)qp;
    qf[1] = *(const f16x8*)(qp + 32);
  }
  float rv[4];
#pragma unroll
  for (int r = 0; r < 4; r++)
    rv[r] = rinv[(size_t)(b * Hh + w) * Nn + n0 + lq * 4 + r];
  f32x4 oacc[4] = {};
  float su[8] = {}, su2[8] = {};
  for (int m0 = 0; m0 < Nn; m0 += 32) {
    {  // QK (bitwise-identical to k_rsum) -> S = exp*rinv -> sS (fp16)
#pragma unroll
      for (int jm = 0; jm < 2; jm++) {
        const unsigned short* kp =
            qkv + (size_t)(b * Nn + m0 + 16 * jm + lm) * QW + INNER + w * DH + lq * 8;
        f16x8 k0 = *(const f16x8*)kp;
        f16x8 k1 = *(const f16x8*)(kp + 32);
        f32x4 lac = {};
        lac = MFMA16(qf[0], k0, lac);
        lac = MFMA16(qf[1], k1, lac);
#pragma unroll
        for (int r = 0; r < 4; r++)
          sS[w][lq * 4 + r][16 * jm + lm] = f2h(__expf(lac[r] * SCALE) * rv[r]);
      }
    }
    __syncthreads();  // sS complete (prev iter's mix readers already past barrier 2)
    {  // mix: thread owns one (n,m); fp32 conv + stats; u -> sU (fp16)
      float sv[8];
#pragma unroll
      for (int h = 0; h < 8; h++) sv[h] = h2f(sS[h][mxn][mxm]);
#pragma unroll
      for (int g = 0; g < 8; g++) {
        float u = 0.f;
#pragma unroll
        for (int h = 0; h < 8; h++) u += cw[g * 8 + h] * sv[h];
        su[g] += u;
        su2[g] += u * u;
        sU[g][mxn][mxm] = f2h(u);
      }
    }
    __syncthreads();  // sU complete
    {  // PV: wave g=w, A = sU[w], B = vT direct from global (L2-hot)
      f16x8 uf = *(const f16x8*)&sU[w][lm][lq * 8];
#pragma unroll
      for (int j = 0; j < 4; j++) {
        const unsigned short* vp =
            vT + (((size_t)(b * Hh + w) * DH + 16 * j + lm) << 10) + m0 + lq * 8;
        f16x8 vv = *(const f16x8*)vp;
        oacc[j] = MFMA16(uf, vv, oacc[j]);
      }
    }
    // no barrier needed here: next iter's sS writes happen after barrier 1,
    // and next mix (which overwrites sU) happens after that barrier too.
  }
#pragma unroll
  for (int j = 0; j < 4; j++)
#pragma unroll
    for (int r = 0; r < 4; r++)
      O1[((size_t)(b * Hh + w) * Nn + n0 + lq * 4 + r) * DH + 16 * j + lm] = oacc[j][r];
#pragma unroll
  for (int g = 0; g < 8; g++) {
    float a = su[g], q = su2[g];
    for (int off = 32; off; off >>= 1) {
      a += __shfl_down(a, off);
      q += __shfl_down(q, off);
    }
    if (l == 0) {
      sRed[w][g] = a;
      sRed[w][8 + g] = q;
    }
  }
  __syncthreads();
  if (t < 16) {
    float s = 0.f;
#pragma unroll
    for (int ww = 0; ww < 8; ww++) s += sRed[ww][t];
    atomicAdd(&stats[t], s);
  }
}

// ---------------- K3: alpha/const ------------------------------------------
__global__ void k_alpha(const float* __restrict__ stats, const float* __restrict__ bn_gamma,
                        const float* __restrict__ bn_beta, float* __restrict__ ac) {
  const int g = threadIdx.x;
  if (g < 8) {
    const float cnt = (float)Bz * (float)Nn * (float)Nn;
    float Eu = stats[g] / cnt;
    float Eu2 = stats[8 + g] / cnt;
    float inv = rsqrtf(Eu2 - Eu * Eu + BN_EPS);
    float alpha = bn_gamma[g] * inv;
    ac[g] = alpha;
    ac[8 + g] = bn_beta[g] - Eu * alpha;
  }
}

// ---------------- k_o1aff: O1hf = fp16(alpha*O1 + c*vsum) ------------------
__global__ __launch_bounds__(256) void k_o1aff(const float* __restrict__ O1,
                                               const float* __restrict__ vsum,
                                               const float* __restrict__ ac,
                                               unsigned short* __restrict__ O1BF) {
  const size_t i4 = ((size_t)blockIdx.x * 256 + threadIdx.x) * 4;
  const int bg = (int)(i4 >> 16);
  const int g = bg & 7;
  const int d = (int)(i4 & 63);
  float4 a = *(const float4*)(O1 + i4);
  float4 v = *(const float4*)(vsum + (size_t)bg * DH + d);
  const float al = ac[g], cc = ac[8 + g];
  unsigned short o[4] = {f2h(al * a.x + cc * v.x), f2h(al * a.y + cc * v.y),
                         f2h(al * a.z + cc * v.z), f2h(al * a.w + cc * v.w)};
  *(uint2*)(O1BF + i4) = *(uint2*)o;
}

// ---------------- K4: out = O1hf @ w_out + b_out (fp16 MFMA) ---------------
__global__ __launch_bounds__(256) void k_out(const unsigned short* __restrict__ O1BF,
                                             const unsigned short* __restrict__ WOT,
                                             const float* __restrict__ bout,
                                             float* __restrict__ out) {
  __shared__ unsigned short sA[128][40];
  __shared__ unsigned short sB[128][40];
  const int t = threadIdx.x;
  const int col0 = blockIdx.x * 128, row0 = blockIdx.y * 128;
  const int l = t & 63, w = t >> 6;
  const int wm = (w & 1) * 64, wn = (w >> 1) * 64;
  const int lm = l & 15, lq = l >> 4;
  const int srow = t >> 1, skc = (t & 1) * 16;
  const int b = row0 >> 10;
  const int nn = (row0 + srow) & 1023;
  f32x4 acc[4][4] = {};
  for (int k0 = 0; k0 < INNER; k0 += 32) {
    {
      const int k = k0 + skc;
      const int g = k >> 6, dd = k & 63;
      const unsigned short* src = O1BF + ((size_t)(b * Hh + g) * Nn + nn) * DH + dd;
      *(uint4*)&sA[srow][skc] = *(const uint4*)src;
      *(uint4*)&sA[srow][skc + 8] = *(const uint4*)(src + 8);
    }
    {
      const unsigned short* srcB = WOT + (size_t)(col0 + srow) * INNER + k0 + skc;
      *(uint4*)&sB[srow][skc] = *(const uint4*)srcB;
      *(uint4*)&sB[srow][skc + 8] = *(const uint4*)(srcB + 8);
    }
    __syncthreads();
    f16x8 af[4], bfr[4];
#pragma unroll
    for (int i = 0; i < 4; i++) af[i] = *(const f16x8*)&sA[wm + 16 * i + lm][lq * 8];
#pragma unroll
    for (int j = 0; j < 4; j++) bfr[j] = *(const f16x8*)&sB[wn + 16 * j + lm][lq * 8];
#pragma unroll
    for (int i = 0; i < 4; i++)
#pragma unroll
      for (int j = 0; j < 4; j++) acc[i][j] = MFMA16(af[i], bfr[j], acc[i][j]);
    __syncthreads();
  }
#pragma unroll
  for (int j = 0; j < 4; j++) {
    const int col = col0 + wn + 16 * j + lm;
    const float bo = bout[col];
#pragma unroll
    for (int i = 0; i < 4; i++) {
      const int rbase = row0 + wm + 16 * i + lq * 4;
#pragma unroll
      for (int r = 0; r < 4; r++) out[(size_t)(rbase + r) * Dd + col] = acc[i][j][r] + bo;
    }
  }
}

extern "C" void kernel_launch(void* const* d_in, const int* in_sizes, int n_in,
                              void* d_out, int out_size, void* d_ws, size_t ws_size,
                              hipStream_t stream) {
  const float* x = (const float*)d_in[0];
  const float* w_qkv = (const float*)d_in[1];
  const float* conv_w = (const float*)d_in[2];
  // d_in[3] = conv_b : cancels in train-mode BN.
  const float* bn_gamma = (const float*)d_in[4];
  const float* bn_beta = (const float*)d_in[5];
  const float* w_out = (const float*)d_in[6];
  const float* b_out = (const float*)d_in[7];
  char* ws = (char*)d_ws;
  unsigned short* XB = (unsigned short*)(ws + WB_XB);
  unsigned short* QKV = (unsigned short*)(ws + WB_QKV);
  unsigned short* VT = (unsigned short*)(ws + WB_VT);
  unsigned short* WQT = (unsigned short*)(ws + WB_WQT);
  unsigned short* WOT = (unsigned short*)(ws + WB_WOT);
  float* O1 = (float*)(ws + WB_O1);
  unsigned short* O1BF = (unsigned short*)(ws + WB_O1BF);
  float* RINV = (float*)(ws + WB_RINV);
  float* VSUM = (float*)(ws + WB_VSUM);
  float* STATS = (float*)(ws + WB_STATS);
  float* AC = (float*)(ws + WB_AC);

  hipMemsetAsync(STATS, 0, 64, stream);
  k_xbf<<<2048, 256, 0, stream>>>(x, XB);
  k_transpose<<<dim3(48, 16), 256, 0, stream>>>(w_qkv, WQT, 512, 1536);
  k_transpose<<<dim3(16, 16), 256, 0, stream>>>(w_out, WOT, 512, 512);
  k_qkv<<<dim3(12, 64), 256, 34816, stream>>>(XB, WQT, QKV, VT);
  k_vsum<<<64, 256, 0, stream>>>(VT, VSUM);
  k_rsum<<<dim3(8, 64), 512, 0, stream>>>(QKV, RINV);
  k_fuse<<<dim3(8, 64), 512, 0, stream>>>(QKV, VT, RINV, conv_w, O1, STATS);
  k_alpha<<<1, 64, 0, stream>>>(STATS, bn_gamma, bn_beta, AC);
  k_o1aff<<<4096, 256, 0, stream>>>(O1, VSUM, AC, O1BF);
  k_out<<<dim3(4, 64), 256, 0, stream>>>(O1BF, WOT, b_out, (float*)d_out);
}